// Round 1
// baseline (687.406 us; speedup 1.0000x reference)
//
#include <hip/hip_runtime.h>
#include <math.h>

// ---------------------------------------------------------------------------
// DeformableFeatureAggregation — MI355X
// Pipeline:
//   k_transpose  x4 : feat (6,256,H,W) -> featT (6,H,W,256)   [channels-last]
//   k_wts_gemm      : logits = instance_feature @ W_wts + b   (4096 x 2496)
//   k_sample        : per-anchor block: softmax(logits), learnable pts,
//                     projection, bilinear gather+weight  -> feats (4096,256)
//   k_out_gemm      : out = feats @ W_out + b_out + instance_feature
// Workspace layout (floats):
//   featT L0..L3 : 0 .. 22978560
//   logits       : 22978560 .. 33202176
//   feats        : 33202176 .. 34250752   (137 MB total)
// ---------------------------------------------------------------------------

#define FEATT_L0 0
#define FEATT_L1 17301504
#define FEATT_L2 21626880
#define FEATT_L3 22708224
#define WS_LOGITS 22978560
#define WS_FEATS 33202176

__device__ const float FIXS[7][3] = {
    {0.f, 0.f, 0.f},  {0.45f, 0.f, 0.f}, {-0.45f, 0.f, 0.f}, {0.f, 0.45f, 0.f},
    {0.f, -0.45f, 0.f}, {0.f, 0.f, 0.45f}, {0.f, 0.f, -0.45f}};

// (6,256,H,W) -> (6,H,W,256)
__global__ __launch_bounds__(256) void k_transpose(const float* __restrict__ src,
                                                   float* __restrict__ dst,
                                                   int H, int W) {
  __shared__ float tile[32][33];
  const int tid = threadIdx.x;
  const int i = tid & 31;
  const int j = tid >> 5;  // 0..7
  const int xt = blockIdx.x * 32;
  const int y = blockIdx.y;
  const int c = blockIdx.z >> 3;
  const int cht = (blockIdx.z & 7) * 32;
#pragma unroll
  for (int jj = j; jj < 32; jj += 8) {
    int x = xt + i;
    float v = 0.f;
    if (x < W) v = src[((c * 256 + cht + jj) * H + y) * W + x];
    tile[jj][i] = v;
  }
  __syncthreads();
#pragma unroll
  for (int jj = j; jj < 32; jj += 8) {
    int x = xt + jj;
    if (x < W) dst[(((c * H + y) * W + x) * 256) + cht + i] = tile[i][jj];
  }
}

// logits = A(4096,256) @ W(256,2496) + bias ; 16 anchors/block, j split in 2
__global__ __launch_bounds__(256) void k_wts_gemm(const float* __restrict__ A,
                                                  const float* __restrict__ W,
                                                  const float* __restrict__ bias,
                                                  float* __restrict__ out) {
  __shared__ float sA[16 * 256];
  const int tid = threadIdx.x;
  const int m0 = blockIdx.y * 16;
  const int jh = blockIdx.x;
  for (int i = tid; i < 16 * 256; i += 256) sA[i] = A[m0 * 256 + i];
  __syncthreads();
  for (int jb = 0; jb < 5; ++jb) {
    const int jl = tid + jb * 256;
    if (jl >= 1248) break;
    const int j = jh * 1248 + jl;
    float acc[16];
#pragma unroll
    for (int m = 0; m < 16; ++m) acc[m] = 0.f;
    for (int k4 = 0; k4 < 64; ++k4) {
      const int k = k4 * 4;
      const float w0 = W[(k + 0) * 2496 + j];
      const float w1 = W[(k + 1) * 2496 + j];
      const float w2 = W[(k + 2) * 2496 + j];
      const float w3 = W[(k + 3) * 2496 + j];
#pragma unroll
      for (int m = 0; m < 16; ++m) {
        const float4 a = *(const float4*)&sA[m * 256 + k];
        acc[m] += a.x * w0 + a.y * w1 + a.z * w2 + a.w * w3;
      }
    }
    const float b = bias[j];
#pragma unroll
    for (int m = 0; m < 16; ++m) out[(m0 + m) * 2496 + j] = acc[m] + b;
  }
}

__global__ __launch_bounds__(256) void k_sample(
    const float* __restrict__ anchor, const float* __restrict__ iw,
    const float* __restrict__ logits, const float* __restrict__ featT,
    const float* __restrict__ proj, const float* __restrict__ wh,
    const float* __restrict__ W_learn, const float* __restrict__ b_learn,
    float* __restrict__ feats) {
  const int n = blockIdx.x;
  const int tid = threadIdx.x;
  const int lane = tid & 63;
  const int wave = tid >> 6;
  __shared__ float s_iw[256];
  __shared__ float s_w[2496];
  __shared__ float s_p2d[78][2];
  __shared__ float s_learn[18];
  __shared__ float s_red[4][256];

  s_iw[tid] = iw[n * 256 + tid];
  for (int i = tid; i < 2496; i += 256) s_w[i] = logits[n * 2496 + i];
  __syncthreads();

  // learnable points: 18 matvec outputs on threads 0..17 (wave 0)
  if (tid < 18) {
    float acc = b_learn[tid];
    for (int k = 0; k < 256; ++k) acc += s_iw[k] * W_learn[k * 18 + tid];
    acc = fminf(fmaxf(acc, -9.21f), 9.21f);
    s_learn[tid] = 1.f / (1.f + expf(-acc)) - 0.5f;
  }
  // softmax over the 312 axis, per group; wave w handles groups 2w,2w+1
#pragma unroll
  for (int gg = 0; gg < 2; ++gg) {
    const int g = wave * 2 + gg;
    float mx = -1e30f;
    for (int s = lane; s < 312; s += 64) mx = fmaxf(mx, s_w[s * 8 + g]);
    for (int off = 32; off; off >>= 1) mx = fmaxf(mx, __shfl_xor(mx, off));
    float sum = 0.f;
    for (int s = lane; s < 312; s += 64) {
      const float e = expf(s_w[s * 8 + g] - mx);
      s_w[s * 8 + g] = e;
      sum += e;
    }
    for (int off = 32; off; off >>= 1) sum += __shfl_xor(sum, off);
    const float inv = 1.f / sum;
    for (int s = lane; s < 312; s += 64) s_w[s * 8 + g] *= inv;
  }
  __syncthreads();

  // projection: 78 (pt,cam) pairs
  if (tid < 78) {
    const int p = tid / 6, c = tid % 6;
    const float* an = anchor + n * 11;
    float qw = an[6], qx = an[7], qy = an[8], qz = an[9];
    const float qinv = 1.f / sqrtf(qw * qw + qx * qx + qy * qy + qz * qz);
    qw *= qinv; qx *= qinv; qy *= qinv; qz *= qinv;
    const float R00 = 1.f - 2.f * (qy * qy + qz * qz), R01 = 2.f * (qx * qy - qw * qz), R02 = 2.f * (qx * qz + qw * qy);
    const float R10 = 2.f * (qx * qy + qw * qz), R11 = 1.f - 2.f * (qx * qx + qz * qz), R12 = 2.f * (qy * qz - qw * qx);
    const float R20 = 2.f * (qx * qz - qw * qy), R21 = 2.f * (qy * qz + qw * qx), R22 = 1.f - 2.f * (qx * qx + qy * qy);
    float s0, s1, s2;
    if (p < 7) {
      s0 = FIXS[p][0]; s1 = FIXS[p][1]; s2 = FIXS[p][2];
    } else {
      const int b = (p - 7) * 3;
      s0 = s_learn[b]; s1 = s_learn[b + 1]; s2 = s_learn[b + 2];
    }
    const float vx = s0 * an[3], vy = s1 * an[4], vz = s2 * an[5];
    // kp = R^T * v + t
    const float kx = R00 * vx + R10 * vy + R20 * vz + an[0];
    const float ky = R01 * vx + R11 * vy + R21 * vz + an[1];
    const float kz = R02 * vx + R12 * vy + R22 * vz + an[2];
    const float* P = proj + c * 16;
    const float h0 = P[0] * kx + P[1] * ky + P[2] * kz + P[3];
    const float h1 = P[4] * kx + P[5] * ky + P[6] * kz + P[7];
    const float h2 = P[8] * kx + P[9] * ky + P[10] * kz + P[11];
    const float zz = fmaxf(h2, 1e-5f);
    float px = h0 / zz / wh[c * 2 + 0];
    float py = h1 / zz / wh[c * 2 + 1];
    px = fminf(fmaxf(px, 0.f), 0.9999f);
    py = fminf(fmaxf(py, 0.f), 0.9999f);
    s_p2d[tid][0] = px;
    s_p2d[tid][1] = py;
  }
  __syncthreads();

  // main gather loop: wave handles (p,c) = wave, wave+4, ...; levels unrolled
  float4 acc = make_float4(0.f, 0.f, 0.f, 0.f);
  const int ch = lane * 4;
  const int g = lane >> 3;  // group of this lane's 4 channels
  for (int pc = wave; pc < 78; pc += 4) {
    const int p = pc / 6, c = pc - p * 6;
    const float px = s_p2d[pc][0], py = s_p2d[pc][1];
    const int wbase = (c * 52 + p) * 8 + g;
    constexpr int LB[4] = {FEATT_L0, FEATT_L1, FEATT_L2, FEATT_L3};
    constexpr int CS[4] = {2883584, 720896, 180224, 45056};  // H*W*256
#pragma unroll
    for (int l = 0; l < 4; ++l) {
      const int H = 64 >> l, W = 176 >> l;
      const float fx = px * (float)W - 0.5f;
      const float fy = py * (float)H - 0.5f;
      const float x0f = floorf(fx), y0f = floorf(fy);
      const float wx = fx - x0f, wy = fy - y0f;
      const int x0 = (int)x0f, y0 = (int)y0f;
      const float mx0 = (x0 >= 0) ? 1.f : 0.f;
      const float mx1 = (x0 + 1 < W) ? 1.f : 0.f;
      const float my0 = (y0 >= 0) ? 1.f : 0.f;
      const float my1 = (y0 + 1 < H) ? 1.f : 0.f;
      const int cx0 = max(x0, 0), cx1 = min(x0 + 1, W - 1);
      const int cy0 = max(y0, 0), cy1 = min(y0 + 1, H - 1);
      const float* bp = featT + LB[l] + c * CS[l];
      const float* r0 = bp + cy0 * (W * 256);
      const float* r1 = bp + cy1 * (W * 256);
      const float4 v00 = *(const float4*)(r0 + cx0 * 256 + ch);
      const float4 v01 = *(const float4*)(r0 + cx1 * 256 + ch);
      const float4 v10 = *(const float4*)(r1 + cx0 * 256 + ch);
      const float4 v11 = *(const float4*)(r1 + cx1 * 256 + ch);
      const float wgt = s_w[wbase + l * 104];
      const float w00 = (1.f - wx) * (1.f - wy) * mx0 * my0 * wgt;
      const float w01 = wx * (1.f - wy) * mx1 * my0 * wgt;
      const float w10 = (1.f - wx) * wy * mx0 * my1 * wgt;
      const float w11 = wx * wy * mx1 * my1 * wgt;
      acc.x += v00.x * w00 + v01.x * w01 + v10.x * w10 + v11.x * w11;
      acc.y += v00.y * w00 + v01.y * w01 + v10.y * w10 + v11.y * w11;
      acc.z += v00.z * w00 + v01.z * w01 + v10.z * w10 + v11.z * w11;
      acc.w += v00.w * w00 + v01.w * w01 + v10.w * w10 + v11.w * w11;
    }
  }
  *(float4*)&s_red[wave][ch] = acc;
  __syncthreads();
  if (wave == 0) {
    float4 r = make_float4(0.f, 0.f, 0.f, 0.f);
#pragma unroll
    for (int w2 = 0; w2 < 4; ++w2) {
      const float4 t = *(const float4*)&s_red[w2][ch];
      r.x += t.x; r.y += t.y; r.z += t.z; r.w += t.w;
    }
    *(float4*)&feats[n * 256 + ch] = r;
  }
}

// out = feats(4096,256) @ W_out(256,256) + b_out + resid ; 8 anchors/block
__global__ __launch_bounds__(256) void k_out_gemm(const float* __restrict__ feats,
                                                  const float* __restrict__ W,
                                                  const float* __restrict__ bias,
                                                  const float* __restrict__ resid,
                                                  float* __restrict__ out) {
  __shared__ float sA[8 * 256];
  const int tid = threadIdx.x;
  const int m0 = blockIdx.x * 8;
  for (int i = tid; i < 8 * 256; i += 256) sA[i] = feats[m0 * 256 + i];
  __syncthreads();
  const int j = tid;
  float acc[8];
#pragma unroll
  for (int m = 0; m < 8; ++m) acc[m] = 0.f;
  for (int k4 = 0; k4 < 64; ++k4) {
    const int k = k4 * 4;
    const float w0 = W[(k + 0) * 256 + j];
    const float w1 = W[(k + 1) * 256 + j];
    const float w2 = W[(k + 2) * 256 + j];
    const float w3 = W[(k + 3) * 256 + j];
#pragma unroll
    for (int m = 0; m < 8; ++m) {
      const float4 a = *(const float4*)&sA[m * 256 + k];
      acc[m] += a.x * w0 + a.y * w1 + a.z * w2 + a.w * w3;
    }
  }
  const float b = bias[j];
#pragma unroll
  for (int m = 0; m < 8; ++m)
    out[(m0 + m) * 256 + j] = acc[m] + b + resid[(m0 + m) * 256 + j];
}

extern "C" void kernel_launch(void* const* d_in, const int* in_sizes, int n_in,
                              void* d_out, int out_size, void* d_ws, size_t ws_size,
                              hipStream_t stream) {
  (void)in_sizes; (void)n_in; (void)out_size; (void)ws_size;
  const float* iw      = (const float*)d_in[1];   // instance_feature (1,4096,256)
  const float* anchor  = (const float*)d_in[2];   // (1,4096,11)
  const float* f0      = (const float*)d_in[3];
  const float* f1      = (const float*)d_in[4];
  const float* f2      = (const float*)d_in[5];
  const float* f3      = (const float*)d_in[6];
  const float* proj    = (const float*)d_in[7];   // (1,6,4,4)
  const float* wh      = (const float*)d_in[8];   // (1,6,2)
  const float* W_learn = (const float*)d_in[9];   // (256,18)
  const float* b_learn = (const float*)d_in[10];  // (18)
  const float* W_wts   = (const float*)d_in[11];  // (256,2496)
  const float* b_wts   = (const float*)d_in[12];  // (2496)
  const float* W_out   = (const float*)d_in[13];  // (256,256)
  const float* b_out   = (const float*)d_in[14];  // (256)
  float* out = (float*)d_out;
  float* ws = (float*)d_ws;
  float* featT  = ws;
  float* logits = ws + WS_LOGITS;
  float* feats  = ws + WS_FEATS;

  k_transpose<<<dim3(6, 64, 48), 256, 0, stream>>>(f0, featT + FEATT_L0, 64, 176);
  k_transpose<<<dim3(3, 32, 48), 256, 0, stream>>>(f1, featT + FEATT_L1, 32, 88);
  k_transpose<<<dim3(2, 16, 48), 256, 0, stream>>>(f2, featT + FEATT_L2, 16, 44);
  k_transpose<<<dim3(1, 8, 48), 256, 0, stream>>>(f3, featT + FEATT_L3, 8, 22);
  k_wts_gemm<<<dim3(2, 256), 256, 0, stream>>>(iw, W_wts, b_wts, logits);
  k_sample<<<4096, 256, 0, stream>>>(anchor, iw, logits, featT, proj, wh,
                                     W_learn, b_learn, feats);
  k_out_gemm<<<512, 256, 0, stream>>>(feats, W_out, b_out, iw, out);
}

// Round 2
// 547.732 us; speedup vs baseline: 1.2550x; 1.2550x over previous
//
#include <hip/hip_runtime.h>
#include <math.h>

// ---------------------------------------------------------------------------
// DeformableFeatureAggregation — MI355X
// Pipeline:
//   k_transpose  x4 : feat (6,256,H,W) -> featT (6,H,W,256)   [channels-last]
//   k_wts_gemm      : logits = instance_feature @ W_wts + b   (4096 x 2496)
//                     register-tiled: 16m x 4j per thread, A broadcast from LDS
//   k_sample        : per-anchor block: softmax(logits), learnable pts,
//                     projection, bilinear gather+weight  -> feats (4096,256)
//   k_out_gemm      : out = feats @ W_out + b_out + instance_feature
// Workspace layout (floats):
//   featT L0..L3 : 0 .. 22978560
//   logits       : 22978560 .. 33202176
//   feats        : 33202176 .. 34250752   (137 MB total)
// ---------------------------------------------------------------------------

#define FEATT_L0 0
#define FEATT_L1 17301504
#define FEATT_L2 21626880
#define FEATT_L3 22708224
#define WS_LOGITS 22978560
#define WS_FEATS 33202176

__device__ const float FIXS[7][3] = {
    {0.f, 0.f, 0.f},  {0.45f, 0.f, 0.f}, {-0.45f, 0.f, 0.f}, {0.f, 0.45f, 0.f},
    {0.f, -0.45f, 0.f}, {0.f, 0.f, 0.45f}, {0.f, 0.f, -0.45f}};

// (6,256,H,W) -> (6,H,W,256)
__global__ __launch_bounds__(256) void k_transpose(const float* __restrict__ src,
                                                   float* __restrict__ dst,
                                                   int H, int W) {
  __shared__ float tile[32][33];
  const int tid = threadIdx.x;
  const int i = tid & 31;
  const int j = tid >> 5;  // 0..7
  const int xt = blockIdx.x * 32;
  const int y = blockIdx.y;
  const int c = blockIdx.z >> 3;
  const int cht = (blockIdx.z & 7) * 32;
#pragma unroll
  for (int jj = j; jj < 32; jj += 8) {
    int x = xt + i;
    float v = 0.f;
    if (x < W) v = src[((c * 256 + cht + jj) * H + y) * W + x];
    tile[jj][i] = v;
  }
  __syncthreads();
#pragma unroll
  for (int jj = j; jj < 32; jj += 8) {
    int x = xt + jj;
    if (x < W) dst[(((c * H + y) * W + x) * 256) + cht + i] = tile[i][jj];
  }
}

// logits = A(4096,256) @ W(256,2496) + bias
// block: 16 rows (m) x 1024 cols (j); thread: 16m x 4j accumulator.
// A-tile staged in LDS, read as wave-uniform float4 broadcast (no conflict).
__global__ __launch_bounds__(256) void k_wts_gemm(const float* __restrict__ A,
                                                  const float* __restrict__ W,
                                                  const float* __restrict__ bias,
                                                  float* __restrict__ out) {
  __shared__ float sA[16 * 256];
  const int tid = threadIdx.x;
  const int m0 = blockIdx.y * 16;
  const int j = blockIdx.x * 1024 + tid * 4;
  // stage A tile (16x256 = 4096 floats = 1024 float4)
  for (int i = tid; i < 1024; i += 256)
    *(float4*)&sA[i * 4] = *(const float4*)&A[m0 * 256 + i * 4];
  __syncthreads();
  if (j >= 2496) return;

  float4 acc[16];
#pragma unroll
  for (int m = 0; m < 16; ++m) acc[m] = make_float4(0.f, 0.f, 0.f, 0.f);

  for (int k = 0; k < 256; k += 4) {
    const float4 w0 = *(const float4*)&W[(k + 0) * 2496 + j];
    const float4 w1 = *(const float4*)&W[(k + 1) * 2496 + j];
    const float4 w2 = *(const float4*)&W[(k + 2) * 2496 + j];
    const float4 w3 = *(const float4*)&W[(k + 3) * 2496 + j];
#pragma unroll
    for (int m = 0; m < 16; ++m) {
      const float4 a = *(const float4*)&sA[m * 256 + k];
      acc[m].x += a.x * w0.x + a.y * w1.x + a.z * w2.x + a.w * w3.x;
      acc[m].y += a.x * w0.y + a.y * w1.y + a.z * w2.y + a.w * w3.y;
      acc[m].z += a.x * w0.z + a.y * w1.z + a.z * w2.z + a.w * w3.z;
      acc[m].w += a.x * w0.w + a.y * w1.w + a.z * w2.w + a.w * w3.w;
    }
  }
  const float4 b = *(const float4*)&bias[j];
#pragma unroll
  for (int m = 0; m < 16; ++m) {
    float4 r = acc[m];
    r.x += b.x; r.y += b.y; r.z += b.z; r.w += b.w;
    *(float4*)&out[(m0 + m) * 2496 + j] = r;
  }
}

__global__ __launch_bounds__(256) void k_sample(
    const float* __restrict__ anchor, const float* __restrict__ iw,
    const float* __restrict__ logits, const float* __restrict__ featT,
    const float* __restrict__ proj, const float* __restrict__ wh,
    const float* __restrict__ W_learn, const float* __restrict__ b_learn,
    float* __restrict__ feats) {
  const int n = blockIdx.x;
  const int tid = threadIdx.x;
  const int lane = tid & 63;
  const int wave = tid >> 6;
  __shared__ float s_iw[256];
  __shared__ float s_w[2496];
  __shared__ float s_p2d[78][2];
  __shared__ float s_learn[18];
  __shared__ float s_red[4][256];

  s_iw[tid] = iw[n * 256 + tid];
  for (int i = tid; i < 2496; i += 256) s_w[i] = logits[n * 2496 + i];
  __syncthreads();

  // learnable points: 18 matvec outputs on threads 0..17 (wave 0)
  if (tid < 18) {
    float acc = b_learn[tid];
    for (int k = 0; k < 256; ++k) acc += s_iw[k] * W_learn[k * 18 + tid];
    acc = fminf(fmaxf(acc, -9.21f), 9.21f);
    s_learn[tid] = 1.f / (1.f + expf(-acc)) - 0.5f;
  }
  // softmax over the 312 axis, per group; wave w handles groups 2w,2w+1
#pragma unroll
  for (int gg = 0; gg < 2; ++gg) {
    const int g = wave * 2 + gg;
    float mx = -1e30f;
    for (int s = lane; s < 312; s += 64) mx = fmaxf(mx, s_w[s * 8 + g]);
    for (int off = 32; off; off >>= 1) mx = fmaxf(mx, __shfl_xor(mx, off));
    float sum = 0.f;
    for (int s = lane; s < 312; s += 64) {
      const float e = expf(s_w[s * 8 + g] - mx);
      s_w[s * 8 + g] = e;
      sum += e;
    }
    for (int off = 32; off; off >>= 1) sum += __shfl_xor(sum, off);
    const float inv = 1.f / sum;
    for (int s = lane; s < 312; s += 64) s_w[s * 8 + g] *= inv;
  }
  __syncthreads();

  // projection: 78 (pt,cam) pairs
  if (tid < 78) {
    const int p = tid / 6, c = tid % 6;
    const float* an = anchor + n * 11;
    float qw = an[6], qx = an[7], qy = an[8], qz = an[9];
    const float qinv = 1.f / sqrtf(qw * qw + qx * qx + qy * qy + qz * qz);
    qw *= qinv; qx *= qinv; qy *= qinv; qz *= qinv;
    const float R00 = 1.f - 2.f * (qy * qy + qz * qz), R01 = 2.f * (qx * qy - qw * qz), R02 = 2.f * (qx * qz + qw * qy);
    const float R10 = 2.f * (qx * qy + qw * qz), R11 = 1.f - 2.f * (qx * qx + qz * qz), R12 = 2.f * (qy * qz - qw * qx);
    const float R20 = 2.f * (qx * qz - qw * qy), R21 = 2.f * (qy * qz + qw * qx), R22 = 1.f - 2.f * (qx * qx + qy * qy);
    float s0, s1, s2;
    if (p < 7) {
      s0 = FIXS[p][0]; s1 = FIXS[p][1]; s2 = FIXS[p][2];
    } else {
      const int b = (p - 7) * 3;
      s0 = s_learn[b]; s1 = s_learn[b + 1]; s2 = s_learn[b + 2];
    }
    const float vx = s0 * an[3], vy = s1 * an[4], vz = s2 * an[5];
    // kp = R^T * v + t
    const float kx = R00 * vx + R10 * vy + R20 * vz + an[0];
    const float ky = R01 * vx + R11 * vy + R21 * vz + an[1];
    const float kz = R02 * vx + R12 * vy + R22 * vz + an[2];
    const float* P = proj + c * 16;
    const float h0 = P[0] * kx + P[1] * ky + P[2] * kz + P[3];
    const float h1 = P[4] * kx + P[5] * ky + P[6] * kz + P[7];
    const float h2 = P[8] * kx + P[9] * ky + P[10] * kz + P[11];
    const float zz = fmaxf(h2, 1e-5f);
    float px = h0 / zz / wh[c * 2 + 0];
    float py = h1 / zz / wh[c * 2 + 1];
    px = fminf(fmaxf(px, 0.f), 0.9999f);
    py = fminf(fmaxf(py, 0.f), 0.9999f);
    s_p2d[tid][0] = px;
    s_p2d[tid][1] = py;
  }
  __syncthreads();

  // main gather loop: wave handles (p,c) = wave, wave+4, ...; levels unrolled
  float4 acc = make_float4(0.f, 0.f, 0.f, 0.f);
  const int ch = lane * 4;
  const int g = lane >> 3;  // group of this lane's 4 channels
  for (int pc = wave; pc < 78; pc += 4) {
    const int p = pc / 6, c = pc - p * 6;
    const float px = s_p2d[pc][0], py = s_p2d[pc][1];
    const int wbase = (c * 52 + p) * 8 + g;
    constexpr int LB[4] = {FEATT_L0, FEATT_L1, FEATT_L2, FEATT_L3};
    constexpr int CS[4] = {2883584, 720896, 180224, 45056};  // H*W*256
#pragma unroll
    for (int l = 0; l < 4; ++l) {
      const int H = 64 >> l, W = 176 >> l;
      const float fx = px * (float)W - 0.5f;
      const float fy = py * (float)H - 0.5f;
      const float x0f = floorf(fx), y0f = floorf(fy);
      const float wx = fx - x0f, wy = fy - y0f;
      const int x0 = (int)x0f, y0 = (int)y0f;
      const float mx0 = (x0 >= 0) ? 1.f : 0.f;
      const float mx1 = (x0 + 1 < W) ? 1.f : 0.f;
      const float my0 = (y0 >= 0) ? 1.f : 0.f;
      const float my1 = (y0 + 1 < H) ? 1.f : 0.f;
      const int cx0 = max(x0, 0), cx1 = min(x0 + 1, W - 1);
      const int cy0 = max(y0, 0), cy1 = min(y0 + 1, H - 1);
      const float* bp = featT + LB[l] + c * CS[l];
      const float* r0 = bp + cy0 * (W * 256);
      const float* r1 = bp + cy1 * (W * 256);
      const float4 v00 = *(const float4*)(r0 + cx0 * 256 + ch);
      const float4 v01 = *(const float4*)(r0 + cx1 * 256 + ch);
      const float4 v10 = *(const float4*)(r1 + cx0 * 256 + ch);
      const float4 v11 = *(const float4*)(r1 + cx1 * 256 + ch);
      const float wgt = s_w[wbase + l * 104];
      const float w00 = (1.f - wx) * (1.f - wy) * mx0 * my0 * wgt;
      const float w01 = wx * (1.f - wy) * mx1 * my0 * wgt;
      const float w10 = (1.f - wx) * wy * mx0 * my1 * wgt;
      const float w11 = wx * wy * mx1 * my1 * wgt;
      acc.x += v00.x * w00 + v01.x * w01 + v10.x * w10 + v11.x * w11;
      acc.y += v00.y * w00 + v01.y * w01 + v10.y * w10 + v11.y * w11;
      acc.z += v00.z * w00 + v01.z * w01 + v10.z * w10 + v11.z * w11;
      acc.w += v00.w * w00 + v01.w * w01 + v10.w * w10 + v11.w * w11;
    }
  }
  *(float4*)&s_red[wave][ch] = acc;
  __syncthreads();
  if (wave == 0) {
    float4 r = make_float4(0.f, 0.f, 0.f, 0.f);
#pragma unroll
    for (int w2 = 0; w2 < 4; ++w2) {
      const float4 t = *(const float4*)&s_red[w2][ch];
      r.x += t.x; r.y += t.y; r.z += t.z; r.w += t.w;
    }
    *(float4*)&feats[n * 256 + ch] = r;
  }
}

// out = feats(4096,256) @ W_out(256,256) + b_out + resid
// block: 8 rows x 256 cols; thread: 2m x 4j; wave-uniform LDS broadcast for A.
__global__ __launch_bounds__(256) void k_out_gemm(const float* __restrict__ feats,
                                                  const float* __restrict__ W,
                                                  const float* __restrict__ bias,
                                                  const float* __restrict__ resid,
                                                  float* __restrict__ out) {
  __shared__ float sA[8 * 256];
  const int tid = threadIdx.x;
  const int m0 = blockIdx.x * 8;
  const int jq = tid & 63;
  const int mg = tid >> 6;  // wave index; rows mg*2, mg*2+1 (wave-uniform)
  const int j = jq * 4;
  for (int i = tid; i < 512; i += 256)
    *(float4*)&sA[i * 4] = *(const float4*)&feats[m0 * 256 + i * 4];
  __syncthreads();

  float4 acc0 = make_float4(0.f, 0.f, 0.f, 0.f);
  float4 acc1 = make_float4(0.f, 0.f, 0.f, 0.f);
  const int r0 = mg * 2, r1 = mg * 2 + 1;
  for (int k = 0; k < 256; k += 4) {
    const float4 w0 = *(const float4*)&W[(k + 0) * 256 + j];
    const float4 w1 = *(const float4*)&W[(k + 1) * 256 + j];
    const float4 w2 = *(const float4*)&W[(k + 2) * 256 + j];
    const float4 w3 = *(const float4*)&W[(k + 3) * 256 + j];
    const float4 a0 = *(const float4*)&sA[r0 * 256 + k];
    const float4 a1 = *(const float4*)&sA[r1 * 256 + k];
    acc0.x += a0.x * w0.x + a0.y * w1.x + a0.z * w2.x + a0.w * w3.x;
    acc0.y += a0.x * w0.y + a0.y * w1.y + a0.z * w2.y + a0.w * w3.y;
    acc0.z += a0.x * w0.z + a0.y * w1.z + a0.z * w2.z + a0.w * w3.z;
    acc0.w += a0.x * w0.w + a0.y * w1.w + a0.z * w2.w + a0.w * w3.w;
    acc1.x += a1.x * w0.x + a1.y * w1.x + a1.z * w2.x + a1.w * w3.x;
    acc1.y += a1.x * w0.y + a1.y * w1.y + a1.z * w2.y + a1.w * w3.y;
    acc1.z += a1.x * w0.z + a1.y * w1.z + a1.z * w2.z + a1.w * w3.z;
    acc1.w += a1.x * w0.w + a1.y * w1.w + a1.z * w2.w + a1.w * w3.w;
  }
  const float4 b = *(const float4*)&bias[j];
  {
    const float4 rs = *(const float4*)&resid[(m0 + r0) * 256 + j];
    float4 r = acc0;
    r.x += b.x + rs.x; r.y += b.y + rs.y; r.z += b.z + rs.z; r.w += b.w + rs.w;
    *(float4*)&out[(m0 + r0) * 256 + j] = r;
  }
  {
    const float4 rs = *(const float4*)&resid[(m0 + r1) * 256 + j];
    float4 r = acc1;
    r.x += b.x + rs.x; r.y += b.y + rs.y; r.z += b.z + rs.z; r.w += b.w + rs.w;
    *(float4*)&out[(m0 + r1) * 256 + j] = r;
  }
}

extern "C" void kernel_launch(void* const* d_in, const int* in_sizes, int n_in,
                              void* d_out, int out_size, void* d_ws, size_t ws_size,
                              hipStream_t stream) {
  (void)in_sizes; (void)n_in; (void)out_size; (void)ws_size;
  const float* iw      = (const float*)d_in[1];   // instance_feature (1,4096,256)
  const float* anchor  = (const float*)d_in[2];   // (1,4096,11)
  const float* f0      = (const float*)d_in[3];
  const float* f1      = (const float*)d_in[4];
  const float* f2      = (const float*)d_in[5];
  const float* f3      = (const float*)d_in[6];
  const float* proj    = (const float*)d_in[7];   // (1,6,4,4)
  const float* wh      = (const float*)d_in[8];   // (1,6,2)
  const float* W_learn = (const float*)d_in[9];   // (256,18)
  const float* b_learn = (const float*)d_in[10];  // (18)
  const float* W_wts   = (const float*)d_in[11];  // (256,2496)
  const float* b_wts   = (const float*)d_in[12];  // (2496)
  const float* W_out   = (const float*)d_in[13];  // (256,256)
  const float* b_out   = (const float*)d_in[14];  // (256)
  float* out = (float*)d_out;
  float* ws = (float*)d_ws;
  float* featT  = ws;
  float* logits = ws + WS_LOGITS;
  float* feats  = ws + WS_FEATS;

  k_transpose<<<dim3(6, 64, 48), 256, 0, stream>>>(f0, featT + FEATT_L0, 64, 176);
  k_transpose<<<dim3(3, 32, 48), 256, 0, stream>>>(f1, featT + FEATT_L1, 32, 88);
  k_transpose<<<dim3(2, 16, 48), 256, 0, stream>>>(f2, featT + FEATT_L2, 16, 44);
  k_transpose<<<dim3(1, 8, 48), 256, 0, stream>>>(f3, featT + FEATT_L3, 8, 22);
  k_wts_gemm<<<dim3(3, 256), 256, 0, stream>>>(iw, W_wts, b_wts, logits);
  k_sample<<<4096, 256, 0, stream>>>(anchor, iw, logits, featT, proj, wh,
                                     W_learn, b_learn, feats);
  k_out_gemm<<<512, 256, 0, stream>>>(feats, W_out, b_out, iw, out);
}

// Round 3
// 510.633 us; speedup vs baseline: 1.3462x; 1.0727x over previous
//
#include <hip/hip_runtime.h>
#include <math.h>

// ---------------------------------------------------------------------------
// DeformableFeatureAggregation — MI355X
// Pipeline:
//   k_transpose  x4 : feat (6,256,H,W) fp32 -> featT (6,H,W,256) bf16 (RTNE)
//   k_wts_gemm      : logits = instance_feature @ W_wts + b   (4096 x 2496)
//   k_learn         : learn  = sigmoid(clip(iw @ W_learn + b)) - 0.5 (4096x18)
//   k_sample        : per-anchor block: transposed softmax, projection,
//                     per-task offset/weight tables, bf16 bilinear gather
//   k_out_gemm      : out = feats @ W_out + b_out + instance_feature
// Workspace layout (float element offsets; featT region holds bf16/ushort):
//   featT  : ushort elements 0 .. 22978560  (= float slots 0 .. 11489280)
//   logits : 22978560 .. 33202176
//   feats  : 33202176 .. 34250752
//   learn  : 34250752 .. 34324480           (~137 MB total)
// ---------------------------------------------------------------------------

#define FEATT_L0 0
#define FEATT_L1 17301504
#define FEATT_L2 21626880
#define FEATT_L3 22708224
#define WS_LOGITS 22978560
#define WS_FEATS 33202176
#define WS_LEARN 34250752

__device__ const float FIXS[7][3] = {
    {0.f, 0.f, 0.f},  {0.45f, 0.f, 0.f}, {-0.45f, 0.f, 0.f}, {0.f, 0.45f, 0.f},
    {0.f, -0.45f, 0.f}, {0.f, 0.f, 0.45f}, {0.f, 0.f, -0.45f}};

__device__ __forceinline__ unsigned short f2bf(float f) {
  unsigned int u = __float_as_uint(f);
  u += 0x7fffu + ((u >> 16) & 1u);  // RTNE
  return (unsigned short)(u >> 16);
}

// (6,256,H,W) fp32 -> (6,H,W,256) bf16
__global__ __launch_bounds__(256) void k_transpose(const float* __restrict__ src,
                                                   unsigned short* __restrict__ dst,
                                                   int H, int W) {
  __shared__ float tile[32][33];
  const int tid = threadIdx.x;
  const int i = tid & 31;
  const int j = tid >> 5;  // 0..7
  const int xt = blockIdx.x * 32;
  const int y = blockIdx.y;
  const int c = blockIdx.z >> 3;
  const int cht = (blockIdx.z & 7) * 32;
#pragma unroll
  for (int jj = j; jj < 32; jj += 8) {
    int x = xt + i;
    float v = 0.f;
    if (x < W) v = src[((c * 256 + cht + jj) * H + y) * W + x];
    tile[jj][i] = v;
  }
  __syncthreads();
#pragma unroll
  for (int jj = j; jj < 32; jj += 8) {
    int x = xt + jj;
    if (x < W) dst[(((c * H + y) * W + x) * 256) + cht + i] = f2bf(tile[i][jj]);
  }
}

// logits = A(4096,256) @ W(256,2496) + bias ; 16m x 4j per thread
__global__ __launch_bounds__(256) void k_wts_gemm(const float* __restrict__ A,
                                                  const float* __restrict__ W,
                                                  const float* __restrict__ bias,
                                                  float* __restrict__ out) {
  __shared__ float sA[16 * 256];
  const int tid = threadIdx.x;
  const int m0 = blockIdx.y * 16;
  const int j = blockIdx.x * 1024 + tid * 4;
  for (int i = tid; i < 1024; i += 256)
    *(float4*)&sA[i * 4] = *(const float4*)&A[m0 * 256 + i * 4];
  __syncthreads();
  if (j >= 2496) return;

  float4 acc[16];
#pragma unroll
  for (int m = 0; m < 16; ++m) acc[m] = make_float4(0.f, 0.f, 0.f, 0.f);

  for (int k = 0; k < 256; k += 4) {
    const float4 w0 = *(const float4*)&W[(k + 0) * 2496 + j];
    const float4 w1 = *(const float4*)&W[(k + 1) * 2496 + j];
    const float4 w2 = *(const float4*)&W[(k + 2) * 2496 + j];
    const float4 w3 = *(const float4*)&W[(k + 3) * 2496 + j];
#pragma unroll
    for (int m = 0; m < 16; ++m) {
      const float4 a = *(const float4*)&sA[m * 256 + k];
      acc[m].x += a.x * w0.x + a.y * w1.x + a.z * w2.x + a.w * w3.x;
      acc[m].y += a.x * w0.y + a.y * w1.y + a.z * w2.y + a.w * w3.y;
      acc[m].z += a.x * w0.z + a.y * w1.z + a.z * w2.z + a.w * w3.z;
      acc[m].w += a.x * w0.w + a.y * w1.w + a.z * w2.w + a.w * w3.w;
    }
  }
  const float4 b = *(const float4*)&bias[j];
#pragma unroll
  for (int m = 0; m < 16; ++m) {
    float4 r = acc[m];
    r.x += b.x; r.y += b.y; r.z += b.z; r.w += b.w;
    *(float4*)&out[(m0 + m) * 2496 + j] = r;
  }
}

// learn = sigmoid(clip(iw @ W_learn + b_learn)) - 0.5 ; (4096,18), 16 anchors/blk
__global__ __launch_bounds__(256) void k_learn(const float* __restrict__ A,
                                               const float* __restrict__ Wl,
                                               const float* __restrict__ bl,
                                               float* __restrict__ learn) {
  __shared__ float sA[16 * 256];
  __shared__ float sW[256 * 18];
  const int tid = threadIdx.x;
  const int m0 = blockIdx.x * 16;
  for (int i = tid; i < 1024; i += 256)
    *(float4*)&sA[i * 4] = *(const float4*)&A[m0 * 256 + i * 4];
  for (int i = tid; i < 4608; i += 256) sW[i] = Wl[i];
  __syncthreads();
  for (int o = tid; o < 288; o += 256) {
    const int m = o / 18, col = o - m * 18;
    float acc = bl[col];
    for (int k = 0; k < 256; ++k) acc += sA[m * 256 + k] * sW[k * 18 + col];
    acc = fminf(fmaxf(acc, -9.21f), 9.21f);
    learn[(m0 + m) * 18 + col] = 1.f / (1.f + expf(-acc)) - 0.5f;
  }
}

__global__ __launch_bounds__(256) void k_sample(
    const float* __restrict__ anchor, const float* __restrict__ logits,
    const float* __restrict__ learn_g, const unsigned short* __restrict__ featT,
    const float* __restrict__ proj, const float* __restrict__ wh,
    float* __restrict__ feats) {
  const int n = blockIdx.x;
  const int tid = threadIdx.x;
  const int lane = tid & 63;
  const int wave = tid >> 6;
  __shared__ float s_w[8 * 328];      // transposed softmax [g][s], s<312, pad 328
  __shared__ float s_p2d[78][2];
  __shared__ float s_learn[18];
  __shared__ int4 s_off[312];        // corner element offsets per task t=pc*4+l
  __shared__ float4 s_wt[312];       // bilinear corner weights per task
  __shared__ float s_red[4][256];

  // phase 1: logits -> transposed LDS; learn -> LDS
  for (int i = tid; i < 2496; i += 256) {
    const int s = i >> 3, g = i & 7;
    s_w[g * 328 + s] = logits[n * 2496 + i];
  }
  if (tid < 18) s_learn[tid] = learn_g[n * 18 + tid];
  __syncthreads();

  // phase 2: softmax over s (312) per group; wave w -> groups 2w, 2w+1
#pragma unroll
  for (int gg = 0; gg < 2; ++gg) {
    float* row = &s_w[(wave * 2 + gg) * 328];
    float mx = -1e30f;
    for (int s = lane; s < 312; s += 64) mx = fmaxf(mx, row[s]);
    for (int off = 32; off; off >>= 1) mx = fmaxf(mx, __shfl_xor(mx, off));
    float sum = 0.f;
    for (int s = lane; s < 312; s += 64) {
      const float e = expf(row[s] - mx);
      row[s] = e;
      sum += e;
    }
    for (int off = 32; off; off >>= 1) sum += __shfl_xor(sum, off);
    const float inv = 1.f / sum;
    for (int s = lane; s < 312; s += 64) row[s] *= inv;
  }

  // phase 3: projection of 78 (pt,cam) pairs (runs on threads 0..77)
  if (tid < 78) {
    const int p = tid / 6, c = tid % 6;
    const float* an = anchor + n * 11;
    float qw = an[6], qx = an[7], qy = an[8], qz = an[9];
    const float qinv = 1.f / sqrtf(qw * qw + qx * qx + qy * qy + qz * qz);
    qw *= qinv; qx *= qinv; qy *= qinv; qz *= qinv;
    const float R00 = 1.f - 2.f * (qy * qy + qz * qz), R01 = 2.f * (qx * qy - qw * qz), R02 = 2.f * (qx * qz + qw * qy);
    const float R10 = 2.f * (qx * qy + qw * qz), R11 = 1.f - 2.f * (qx * qx + qz * qz), R12 = 2.f * (qy * qz - qw * qx);
    const float R20 = 2.f * (qx * qz - qw * qy), R21 = 2.f * (qy * qz + qw * qx), R22 = 1.f - 2.f * (qx * qx + qy * qy);
    float s0, s1, s2;
    if (p < 7) {
      s0 = FIXS[p][0]; s1 = FIXS[p][1]; s2 = FIXS[p][2];
    } else {
      const int b = (p - 7) * 3;
      s0 = s_learn[b]; s1 = s_learn[b + 1]; s2 = s_learn[b + 2];
    }
    const float vx = s0 * an[3], vy = s1 * an[4], vz = s2 * an[5];
    const float kx = R00 * vx + R10 * vy + R20 * vz + an[0];
    const float ky = R01 * vx + R11 * vy + R21 * vz + an[1];
    const float kz = R02 * vx + R12 * vy + R22 * vz + an[2];
    const float* P = proj + c * 16;
    const float h0 = P[0] * kx + P[1] * ky + P[2] * kz + P[3];
    const float h1 = P[4] * kx + P[5] * ky + P[6] * kz + P[7];
    const float h2 = P[8] * kx + P[9] * ky + P[10] * kz + P[11];
    const float zz = fmaxf(h2, 1e-5f);
    float px = h0 / zz / wh[c * 2 + 0];
    float py = h1 / zz / wh[c * 2 + 1];
    px = fminf(fmaxf(px, 0.f), 0.9999f);
    py = fminf(fmaxf(py, 0.f), 0.9999f);
    s_p2d[tid][0] = px;
    s_p2d[tid][1] = py;
  }
  __syncthreads();

  // phase 4: per-task (pc,l) corner offsets + bilinear weights (312 tasks)
  {
    constexpr int LB[4] = {FEATT_L0, FEATT_L1, FEATT_L2, FEATT_L3};
    constexpr int CS[4] = {2883584, 720896, 180224, 45056};  // H*W*256
    for (int t = tid; t < 312; t += 256) {
      const int pc = t >> 2, l = t & 3;
      const int c = pc % 6;
      const int H = 64 >> l, W = 176 >> l;
      const float fx = s_p2d[pc][0] * (float)W - 0.5f;
      const float fy = s_p2d[pc][1] * (float)H - 0.5f;
      const float x0f = floorf(fx), y0f = floorf(fy);
      const float wx = fx - x0f, wy = fy - y0f;
      const int x0 = (int)x0f, y0 = (int)y0f;
      const float mx0 = (x0 >= 0) ? 1.f : 0.f;
      const float mx1 = (x0 + 1 < W) ? 1.f : 0.f;
      const float my0 = (y0 >= 0) ? 1.f : 0.f;
      const float my1 = (y0 + 1 < H) ? 1.f : 0.f;
      const int cx0 = max(x0, 0), cx1 = min(x0 + 1, W - 1);
      const int cy0 = max(y0, 0), cy1 = min(y0 + 1, H - 1);
      const int base = LB[l] + c * CS[l];
      int4 o;
      o.x = base + (cy0 * W + cx0) * 256;
      o.y = base + (cy0 * W + cx1) * 256;
      o.z = base + (cy1 * W + cx0) * 256;
      o.w = base + (cy1 * W + cx1) * 256;
      s_off[t] = o;
      float4 w4;
      w4.x = (1.f - wx) * (1.f - wy) * mx0 * my0;
      w4.y = wx * (1.f - wy) * mx1 * my0;
      w4.z = (1.f - wx) * wy * mx0 * my1;
      w4.w = wx * wy * mx1 * my1;
      s_wt[t] = w4;
    }
  }
  __syncthreads();

  // phase 5: gather. wave handles pc = wave, wave+4, ... (all 4 levels each)
  float4 acc = make_float4(0.f, 0.f, 0.f, 0.f);
  const int ch = lane * 4;
  const int g = lane >> 3;
  const float* wrow = &s_w[g * 328];
  for (int pc = wave; pc < 78; pc += 4) {
    const int p = pc / 6, c = pc - p * 6;
    const int sbase = c * 52 + p;
#pragma unroll
    for (int l = 0; l < 4; ++l) {
      const int t = pc * 4 + l;
      const int4 o = s_off[t];
      const float4 w = s_wt[t];
      const float wgt = wrow[sbase + l * 13];
      const uint2 u00 = *(const uint2*)(featT + o.x + ch);
      const uint2 u01 = *(const uint2*)(featT + o.y + ch);
      const uint2 u10 = *(const uint2*)(featT + o.z + ch);
      const uint2 u11 = *(const uint2*)(featT + o.w + ch);
#define BF_LO(u) __uint_as_float((u) << 16)
#define BF_HI(u) __uint_as_float((u) & 0xffff0000u)
      const float b0 = BF_LO(u00.x) * w.x + BF_LO(u01.x) * w.y + BF_LO(u10.x) * w.z + BF_LO(u11.x) * w.w;
      const float b1 = BF_HI(u00.x) * w.x + BF_HI(u01.x) * w.y + BF_HI(u10.x) * w.z + BF_HI(u11.x) * w.w;
      const float b2 = BF_LO(u00.y) * w.x + BF_LO(u01.y) * w.y + BF_LO(u10.y) * w.z + BF_LO(u11.y) * w.w;
      const float b3 = BF_HI(u00.y) * w.x + BF_HI(u01.y) * w.y + BF_HI(u10.y) * w.z + BF_HI(u11.y) * w.w;
#undef BF_LO
#undef BF_HI
      acc.x += b0 * wgt;
      acc.y += b1 * wgt;
      acc.z += b2 * wgt;
      acc.w += b3 * wgt;
    }
  }
  *(float4*)&s_red[wave][ch] = acc;
  __syncthreads();
  if (wave == 0) {
    float4 r = make_float4(0.f, 0.f, 0.f, 0.f);
#pragma unroll
    for (int w2 = 0; w2 < 4; ++w2) {
      const float4 t = *(const float4*)&s_red[w2][ch];
      r.x += t.x; r.y += t.y; r.z += t.z; r.w += t.w;
    }
    *(float4*)&feats[n * 256 + ch] = r;
  }
}

// out = feats(4096,256) @ W_out(256,256) + b_out + resid ; 2m x 4j per thread
__global__ __launch_bounds__(256) void k_out_gemm(const float* __restrict__ feats,
                                                  const float* __restrict__ W,
                                                  const float* __restrict__ bias,
                                                  const float* __restrict__ resid,
                                                  float* __restrict__ out) {
  __shared__ float sA[8 * 256];
  const int tid = threadIdx.x;
  const int m0 = blockIdx.x * 8;
  const int jq = tid & 63;
  const int mg = tid >> 6;
  const int j = jq * 4;
  for (int i = tid; i < 512; i += 256)
    *(float4*)&sA[i * 4] = *(const float4*)&feats[m0 * 256 + i * 4];
  __syncthreads();

  float4 acc0 = make_float4(0.f, 0.f, 0.f, 0.f);
  float4 acc1 = make_float4(0.f, 0.f, 0.f, 0.f);
  const int r0 = mg * 2, r1 = mg * 2 + 1;
  for (int k = 0; k < 256; k += 4) {
    const float4 w0 = *(const float4*)&W[(k + 0) * 256 + j];
    const float4 w1 = *(const float4*)&W[(k + 1) * 256 + j];
    const float4 w2 = *(const float4*)&W[(k + 2) * 256 + j];
    const float4 w3 = *(const float4*)&W[(k + 3) * 256 + j];
    const float4 a0 = *(const float4*)&sA[r0 * 256 + k];
    const float4 a1 = *(const float4*)&sA[r1 * 256 + k];
    acc0.x += a0.x * w0.x + a0.y * w1.x + a0.z * w2.x + a0.w * w3.x;
    acc0.y += a0.x * w0.y + a0.y * w1.y + a0.z * w2.y + a0.w * w3.y;
    acc0.z += a0.x * w0.z + a0.y * w1.z + a0.z * w2.z + a0.w * w3.z;
    acc0.w += a0.x * w0.w + a0.y * w1.w + a0.z * w2.w + a0.w * w3.w;
    acc1.x += a1.x * w0.x + a1.y * w1.x + a1.z * w2.x + a1.w * w3.x;
    acc1.y += a1.x * w0.y + a1.y * w1.y + a1.z * w2.y + a1.w * w3.y;
    acc1.z += a1.x * w0.z + a1.y * w1.z + a1.z * w2.z + a1.w * w3.z;
    acc1.w += a1.x * w0.w + a1.y * w1.w + a1.z * w2.w + a1.w * w3.w;
  }
  const float4 b = *(const float4*)&bias[j];
  {
    const float4 rs = *(const float4*)&resid[(m0 + r0) * 256 + j];
    float4 r = acc0;
    r.x += b.x + rs.x; r.y += b.y + rs.y; r.z += b.z + rs.z; r.w += b.w + rs.w;
    *(float4*)&out[(m0 + r0) * 256 + j] = r;
  }
  {
    const float4 rs = *(const float4*)&resid[(m0 + r1) * 256 + j];
    float4 r = acc1;
    r.x += b.x + rs.x; r.y += b.y + rs.y; r.z += b.z + rs.z; r.w += b.w + rs.w;
    *(float4*)&out[(m0 + r1) * 256 + j] = r;
  }
}

extern "C" void kernel_launch(void* const* d_in, const int* in_sizes, int n_in,
                              void* d_out, int out_size, void* d_ws, size_t ws_size,
                              hipStream_t stream) {
  (void)in_sizes; (void)n_in; (void)out_size; (void)ws_size;
  const float* iw      = (const float*)d_in[1];
  const float* anchor  = (const float*)d_in[2];
  const float* f0      = (const float*)d_in[3];
  const float* f1      = (const float*)d_in[4];
  const float* f2      = (const float*)d_in[5];
  const float* f3      = (const float*)d_in[6];
  const float* proj    = (const float*)d_in[7];
  const float* wh      = (const float*)d_in[8];
  const float* W_learn = (const float*)d_in[9];
  const float* b_learn = (const float*)d_in[10];
  const float* W_wts   = (const float*)d_in[11];
  const float* b_wts   = (const float*)d_in[12];
  const float* W_out   = (const float*)d_in[13];
  const float* b_out   = (const float*)d_in[14];
  float* out = (float*)d_out;
  float* ws = (float*)d_ws;
  unsigned short* featT = (unsigned short*)ws;   // bf16 element indices
  float* logits = ws + WS_LOGITS;
  float* feats  = ws + WS_FEATS;
  float* learn  = ws + WS_LEARN;

  k_transpose<<<dim3(6, 64, 48), 256, 0, stream>>>(f0, featT + FEATT_L0, 64, 176);
  k_transpose<<<dim3(3, 32, 48), 256, 0, stream>>>(f1, featT + FEATT_L1, 32, 88);
  k_transpose<<<dim3(2, 16, 48), 256, 0, stream>>>(f2, featT + FEATT_L2, 16, 44);
  k_transpose<<<dim3(1, 8, 48), 256, 0, stream>>>(f3, featT + FEATT_L3, 8, 22);
  k_wts_gemm<<<dim3(3, 256), 256, 0, stream>>>(iw, W_wts, b_wts, logits);
  k_learn<<<256, 256, 0, stream>>>(iw, W_learn, b_learn, learn);
  k_sample<<<4096, 256, 0, stream>>>(anchor, logits, learn, featT, proj, wh, feats);
  k_out_gemm<<<512, 256, 0, stream>>>(feats, W_out, b_out, iw, out);
}

// Round 4
// 492.133 us; speedup vs baseline: 1.3968x; 1.0376x over previous
//
#include <hip/hip_runtime.h>
#include <math.h>

// ---------------------------------------------------------------------------
// DeformableFeatureAggregation — MI355X
// Pipeline:
//   k_transpose  x4 : feat (6,256,H,W) fp32 -> featT (6,H,W,256) bf16 (RTNE)
//   k_wts_gemm      : logits = instance_feature @ W_wts + b   (4096 x 2496)
//                     A read via wave-uniform global loads (s_load broadcast),
//                     no LDS — removes the ds_read_b128 throughput bottleneck
//   k_learn         : learn  = sigmoid(clip(iw @ W_learn + b)) - 0.5 (4096x18)
//   k_sample        : per-anchor block: bf16 transposed softmax, projection,
//                     per-task BYTE offset/weight tables, bf16 gather with
//                     packed-f32 (v_pk_fma_f32) blend
//   k_out_gemm      : out = feats @ W_out + b_out + instance_feature (no LDS)
// Workspace layout (float element offsets; featT region holds bf16/ushort):
//   featT  : ushort elements 0 .. 22978560  (= float slots 0 .. 11489280)
//   logits : 22978560 .. 33202176
//   feats  : 33202176 .. 34250752
//   learn  : 34250752 .. 34324480           (~137 MB total)
// ---------------------------------------------------------------------------

#define FEATT_L0 0
#define FEATT_L1 17301504
#define FEATT_L2 21626880
#define FEATT_L3 22708224
#define WS_LOGITS 22978560
#define WS_FEATS 33202176
#define WS_LEARN 34250752

typedef float v2f __attribute__((ext_vector_type(2)));

__device__ const float FIXS[7][3] = {
    {0.f, 0.f, 0.f},  {0.45f, 0.f, 0.f}, {-0.45f, 0.f, 0.f}, {0.f, 0.45f, 0.f},
    {0.f, -0.45f, 0.f}, {0.f, 0.f, 0.45f}, {0.f, 0.f, -0.45f}};

__device__ __forceinline__ unsigned short f2bf(float f) {
  unsigned int u = __float_as_uint(f);
  u += 0x7fffu + ((u >> 16) & 1u);  // RTNE
  return (unsigned short)(u >> 16);
}
__device__ __forceinline__ float bf2f(unsigned short u) {
  return __uint_as_float(((unsigned int)u) << 16);
}

// (6,256,H,W) fp32 -> (6,H,W,256) bf16
__global__ __launch_bounds__(256) void k_transpose(const float* __restrict__ src,
                                                   unsigned short* __restrict__ dst,
                                                   int H, int W) {
  __shared__ float tile[32][33];
  const int tid = threadIdx.x;
  const int i = tid & 31;
  const int j = tid >> 5;  // 0..7
  const int xt = blockIdx.x * 32;
  const int y = blockIdx.y;
  const int c = blockIdx.z >> 3;
  const int cht = (blockIdx.z & 7) * 32;
#pragma unroll
  for (int jj = j; jj < 32; jj += 8) {
    int x = xt + i;
    float v = 0.f;
    if (x < W) v = src[((c * 256 + cht + jj) * H + y) * W + x];
    tile[jj][i] = v;
  }
  __syncthreads();
#pragma unroll
  for (int jj = j; jj < 32; jj += 8) {
    int x = xt + jj;
    if (x < W) dst[(((c * H + y) * W + x) * 256) + cht + i] = f2bf(tile[i][jj]);
  }
}

// logits = A(4096,256) @ W(256,2496) + bias ; 16m x 4j per thread.
// A addresses are wave-uniform -> compiler emits s_load (SGPR broadcast); the
// FMA takes 1 SGPR operand for free. No LDS, no barrier.
__global__ __launch_bounds__(256) void k_wts_gemm(const float* __restrict__ A,
                                                  const float* __restrict__ W,
                                                  const float* __restrict__ bias,
                                                  float* __restrict__ out) {
  const int tid = threadIdx.x;
  const int m0 = blockIdx.y * 16;
  const int j = blockIdx.x * 1024 + tid * 4;
  if (j >= 2496) return;

  float4 acc[16];
#pragma unroll
  for (int m = 0; m < 16; ++m) acc[m] = make_float4(0.f, 0.f, 0.f, 0.f);
  const float* __restrict__ Ab = A + m0 * 256;

  for (int k = 0; k < 256; k += 4) {
    const float4 w0 = *(const float4*)&W[(k + 0) * 2496 + j];
    const float4 w1 = *(const float4*)&W[(k + 1) * 2496 + j];
    const float4 w2 = *(const float4*)&W[(k + 2) * 2496 + j];
    const float4 w3 = *(const float4*)&W[(k + 3) * 2496 + j];
#pragma unroll
    for (int m = 0; m < 16; ++m) {
      const float4 a = *(const float4*)&Ab[m * 256 + k];  // uniform -> s_load
      acc[m].x += a.x * w0.x + a.y * w1.x + a.z * w2.x + a.w * w3.x;
      acc[m].y += a.x * w0.y + a.y * w1.y + a.z * w2.y + a.w * w3.y;
      acc[m].z += a.x * w0.z + a.y * w1.z + a.z * w2.z + a.w * w3.z;
      acc[m].w += a.x * w0.w + a.y * w1.w + a.z * w2.w + a.w * w3.w;
    }
  }
  const float4 b = *(const float4*)&bias[j];
#pragma unroll
  for (int m = 0; m < 16; ++m) {
    float4 r = acc[m];
    r.x += b.x; r.y += b.y; r.z += b.z; r.w += b.w;
    *(float4*)&out[(m0 + m) * 2496 + j] = r;
  }
}

// learn = sigmoid(clip(iw @ W_learn + b_learn)) - 0.5 ; (4096,18), 16 anchors/blk
__global__ __launch_bounds__(256) void k_learn(const float* __restrict__ A,
                                               const float* __restrict__ Wl,
                                               const float* __restrict__ bl,
                                               float* __restrict__ learn) {
  __shared__ float sA[16 * 256];
  __shared__ float sW[256 * 18];
  const int tid = threadIdx.x;
  const int m0 = blockIdx.x * 16;
  for (int i = tid; i < 1024; i += 256)
    *(float4*)&sA[i * 4] = *(const float4*)&A[m0 * 256 + i * 4];
  for (int i = tid; i < 4608; i += 256) sW[i] = Wl[i];
  __syncthreads();
  for (int o = tid; o < 288; o += 256) {
    const int m = o / 18, col = o - m * 18;
    float acc = bl[col];
    for (int k = 0; k < 256; ++k) acc += sA[m * 256 + k] * sW[k * 18 + col];
    acc = fminf(fmaxf(acc, -9.21f), 9.21f);
    learn[(m0 + m) * 18 + col] = 1.f / (1.f + expf(-acc)) - 0.5f;
  }
}

__global__ __launch_bounds__(256, 6) void k_sample(
    const float* __restrict__ anchor, const float* __restrict__ logits,
    const float* __restrict__ learn_g, const unsigned short* __restrict__ featT,
    const float* __restrict__ proj, const float* __restrict__ wh,
    float* __restrict__ feats) {
  const int n = blockIdx.x;
  const int tid = threadIdx.x;
  const int lane = tid & 63;
  const int wave = tid >> 6;
  __shared__ unsigned short s_w[8 * 328];  // bf16 softmax weights [g][s], pad 328
  __shared__ float s_p2d[78][2];
  __shared__ float s_learn[18];
  __shared__ int4 s_off[312];    // corner BYTE offsets per task t=pc*4+l
  __shared__ float4 s_wt[312];   // bilinear corner weights per task
  __shared__ float s_red[4][256];

  // phase 1: logits -> transposed bf16 LDS; learn -> LDS
  for (int i = tid; i < 2496; i += 256) {
    const int s = i >> 3, g = i & 7;
    s_w[g * 328 + s] = f2bf(logits[n * 2496 + i]);
  }
  if (tid < 18) s_learn[tid] = learn_g[n * 18 + tid];
  __syncthreads();

  // phase 2: softmax over s (312) per group; wave w -> groups 2w, 2w+1.
  // values held in registers between passes; single LDS write-back.
#pragma unroll
  for (int gg = 0; gg < 2; ++gg) {
    unsigned short* row = &s_w[(wave * 2 + gg) * 328];
    float l[5];
    float mx = -1e30f;
#pragma unroll
    for (int i = 0; i < 5; ++i) {
      const int s = lane + i * 64;
      l[i] = (s < 312) ? bf2f(row[s]) : -1e30f;
      mx = fmaxf(mx, l[i]);
    }
    for (int off = 32; off; off >>= 1) mx = fmaxf(mx, __shfl_xor(mx, off));
    float sum = 0.f;
#pragma unroll
    for (int i = 0; i < 5; ++i) {
      l[i] = __expf(l[i] - mx);
      sum += l[i];
    }
    for (int off = 32; off; off >>= 1) sum += __shfl_xor(sum, off);
    const float inv = 1.f / sum;
#pragma unroll
    for (int i = 0; i < 5; ++i) {
      const int s = lane + i * 64;
      if (s < 312) row[s] = f2bf(l[i] * inv);
    }
  }

  // phase 3: projection of 78 (pt,cam) pairs (threads 0..77; same waves 0/1)
  if (tid < 78) {
    const int p = tid / 6, c = tid % 6;
    const float* an = anchor + n * 11;
    float qw = an[6], qx = an[7], qy = an[8], qz = an[9];
    const float qinv = 1.f / sqrtf(qw * qw + qx * qx + qy * qy + qz * qz);
    qw *= qinv; qx *= qinv; qy *= qinv; qz *= qinv;
    const float R00 = 1.f - 2.f * (qy * qy + qz * qz), R01 = 2.f * (qx * qy - qw * qz), R02 = 2.f * (qx * qz + qw * qy);
    const float R10 = 2.f * (qx * qy + qw * qz), R11 = 1.f - 2.f * (qx * qx + qz * qz), R12 = 2.f * (qy * qz - qw * qx);
    const float R20 = 2.f * (qx * qz - qw * qy), R21 = 2.f * (qy * qz + qw * qx), R22 = 1.f - 2.f * (qx * qx + qy * qy);
    float s0, s1, s2;
    if (p < 7) {
      s0 = FIXS[p][0]; s1 = FIXS[p][1]; s2 = FIXS[p][2];
    } else {
      const int b = (p - 7) * 3;
      s0 = s_learn[b]; s1 = s_learn[b + 1]; s2 = s_learn[b + 2];
    }
    const float vx = s0 * an[3], vy = s1 * an[4], vz = s2 * an[5];
    const float kx = R00 * vx + R10 * vy + R20 * vz + an[0];
    const float ky = R01 * vx + R11 * vy + R21 * vz + an[1];
    const float kz = R02 * vx + R12 * vy + R22 * vz + an[2];
    const float* P = proj + c * 16;
    const float h0 = P[0] * kx + P[1] * ky + P[2] * kz + P[3];
    const float h1 = P[4] * kx + P[5] * ky + P[6] * kz + P[7];
    const float h2 = P[8] * kx + P[9] * ky + P[10] * kz + P[11];
    const float zz = fmaxf(h2, 1e-5f);
    float px = h0 / zz / wh[c * 2 + 0];
    float py = h1 / zz / wh[c * 2 + 1];
    px = fminf(fmaxf(px, 0.f), 0.9999f);
    py = fminf(fmaxf(py, 0.f), 0.9999f);
    s_p2d[tid][0] = px;
    s_p2d[tid][1] = py;
  }
  __syncthreads();

  // phase 4: per-task (pc,l) corner BYTE offsets + bilinear weights (312 tasks)
  {
    constexpr int LBB[4] = {0, 34603008, 43253760, 45416448};       // bytes
    constexpr int CSB[4] = {5767168, 1441792, 360448, 90112};        // H*W*512
    for (int t = tid; t < 312; t += 256) {
      const int pc = t >> 2, l = t & 3;
      const int c = pc % 6;
      const int H = 64 >> l, W = 176 >> l;
      const float fx = s_p2d[pc][0] * (float)W - 0.5f;
      const float fy = s_p2d[pc][1] * (float)H - 0.5f;
      const float x0f = floorf(fx), y0f = floorf(fy);
      const float wx = fx - x0f, wy = fy - y0f;
      const int x0 = (int)x0f, y0 = (int)y0f;
      const float mx0 = (x0 >= 0) ? 1.f : 0.f;
      const float mx1 = (x0 + 1 < W) ? 1.f : 0.f;
      const float my0 = (y0 >= 0) ? 1.f : 0.f;
      const float my1 = (y0 + 1 < H) ? 1.f : 0.f;
      const int cx0 = max(x0, 0), cx1 = min(x0 + 1, W - 1);
      const int cy0 = max(y0, 0), cy1 = min(y0 + 1, H - 1);
      const int base = LBB[l] + c * CSB[l];
      int4 o;
      o.x = base + (cy0 * W + cx0) * 512;
      o.y = base + (cy0 * W + cx1) * 512;
      o.z = base + (cy1 * W + cx0) * 512;
      o.w = base + (cy1 * W + cx1) * 512;
      s_off[t] = o;
      float4 w4;
      w4.x = (1.f - wx) * (1.f - wy) * mx0 * my0;
      w4.y = wx * (1.f - wy) * mx1 * my0;
      w4.z = (1.f - wx) * wy * mx0 * my1;
      w4.w = wx * wy * mx1 * my1;
      s_wt[t] = w4;
    }
  }
  __syncthreads();

  // phase 5: gather. wave handles pc = wave, wave+4, ...; packed-f32 blend.
  // bf16 unpack: lo = u<<16; hi = raw u (dirty low mantissa, rel err 2^-8).
  v2f a01 = {0.f, 0.f}, a23 = {0.f, 0.f};
  const int chb = lane * 8;  // byte offset of this lane's 4 bf16 channels
  const int g = lane >> 3;
  const unsigned char* fb = (const unsigned char*)featT;
  const unsigned short* wrow = &s_w[g * 328];
  for (int pc = wave; pc < 78; pc += 4) {
    const int p = pc / 6, c = pc - p * 6;
    const int sb = c * 52 + p;
#pragma unroll
    for (int l4 = 0; l4 < 4; ++l4) {
      const int t = pc * 4 + l4;
      const int4 o = s_off[t];
      const float4 w = s_wt[t];
      const float wg = bf2f(wrow[sb + l4 * 13]);
      const uint2 u0 = *(const uint2*)(fb + (o.x + chb));
      const uint2 u1 = *(const uint2*)(fb + (o.y + chb));
      const uint2 u2 = *(const uint2*)(fb + (o.z + chb));
      const uint2 u3 = *(const uint2*)(fb + (o.w + chb));
      const float w0 = w.x * wg, w1 = w.y * wg, w2 = w.z * wg, w3 = w.w * wg;
      v2f p0, p1, p2, p3, q0, q1, q2, q3;
      p0.x = __uint_as_float(u0.x << 16); p0.y = __uint_as_float(u0.x);
      q0.x = __uint_as_float(u0.y << 16); q0.y = __uint_as_float(u0.y);
      p1.x = __uint_as_float(u1.x << 16); p1.y = __uint_as_float(u1.x);
      q1.x = __uint_as_float(u1.y << 16); q1.y = __uint_as_float(u1.y);
      p2.x = __uint_as_float(u2.x << 16); p2.y = __uint_as_float(u2.x);
      q2.x = __uint_as_float(u2.y << 16); q2.y = __uint_as_float(u2.y);
      p3.x = __uint_as_float(u3.x << 16); p3.y = __uint_as_float(u3.x);
      q3.x = __uint_as_float(u3.y << 16); q3.y = __uint_as_float(u3.y);
      a01 += p0 * w0; a23 += q0 * w0;
      a01 += p1 * w1; a23 += q1 * w1;
      a01 += p2 * w2; a23 += q2 * w2;
      a01 += p3 * w3; a23 += q3 * w3;
    }
  }
  const int ch4 = lane * 4;
  *(float4*)&s_red[wave][ch4] = make_float4(a01.x, a01.y, a23.x, a23.y);
  __syncthreads();
  if (wave == 0) {
    float4 r = make_float4(0.f, 0.f, 0.f, 0.f);
#pragma unroll
    for (int w2 = 0; w2 < 4; ++w2) {
      const float4 t = *(const float4*)&s_red[w2][ch4];
      r.x += t.x; r.y += t.y; r.z += t.z; r.w += t.w;
    }
    *(float4*)&feats[n * 256 + ch4] = r;
  }
}

// out = feats(4096,256) @ W_out(256,256) + b_out + resid ; 2m x 4j per thread.
// feats rows are wave-uniform -> s_load broadcast, no LDS.
__global__ __launch_bounds__(256) void k_out_gemm(const float* __restrict__ feats,
                                                  const float* __restrict__ W,
                                                  const float* __restrict__ bias,
                                                  const float* __restrict__ resid,
                                                  float* __restrict__ out) {
  const int tid = threadIdx.x;
  const int m0 = blockIdx.x * 8;
  const int jq = tid & 63;
  const int mg = tid >> 6;  // wave index; rows mg*2, mg*2+1 (wave-uniform)
  const int j = jq * 4;
  const int r0 = mg * 2, r1 = mg * 2 + 1;
  const float* __restrict__ A0 = feats + (m0 + r0) * 256;
  const float* __restrict__ A1 = feats + (m0 + r1) * 256;

  float4 acc0 = make_float4(0.f, 0.f, 0.f, 0.f);
  float4 acc1 = make_float4(0.f, 0.f, 0.f, 0.f);
  for (int k = 0; k < 256; k += 4) {
    const float4 w0 = *(const float4*)&W[(k + 0) * 256 + j];
    const float4 w1 = *(const float4*)&W[(k + 1) * 256 + j];
    const float4 w2 = *(const float4*)&W[(k + 2) * 256 + j];
    const float4 w3 = *(const float4*)&W[(k + 3) * 256 + j];
    const float4 a0 = *(const float4*)&A0[k];  // uniform -> s_load
    const float4 a1 = *(const float4*)&A1[k];
    acc0.x += a0.x * w0.x + a0.y * w1.x + a0.z * w2.x + a0.w * w3.x;
    acc0.y += a0.x * w0.y + a0.y * w1.y + a0.z * w2.y + a0.w * w3.y;
    acc0.z += a0.x * w0.z + a0.y * w1.z + a0.z * w2.z + a0.w * w3.z;
    acc0.w += a0.x * w0.w + a0.y * w1.w + a0.z * w2.w + a0.w * w3.w;
    acc1.x += a1.x * w0.x + a1.y * w1.x + a1.z * w2.x + a1.w * w3.x;
    acc1.y += a1.x * w0.y + a1.y * w1.y + a1.z * w2.y + a1.w * w3.y;
    acc1.z += a1.x * w0.z + a1.y * w1.z + a1.z * w2.z + a1.w * w3.z;
    acc1.w += a1.x * w0.w + a1.y * w1.w + a1.z * w2.w + a1.w * w3.w;
  }
  const float4 b = *(const float4*)&bias[j];
  {
    const float4 rs = *(const float4*)&resid[(m0 + r0) * 256 + j];
    float4 r = acc0;
    r.x += b.x + rs.x; r.y += b.y + rs.y; r.z += b.z + rs.z; r.w += b.w + rs.w;
    *(float4*)&out[(m0 + r0) * 256 + j] = r;
  }
  {
    const float4 rs = *(const float4*)&resid[(m0 + r1) * 256 + j];
    float4 r = acc1;
    r.x += b.x + rs.x; r.y += b.y + rs.y; r.z += b.z + rs.z; r.w += b.w + rs.w;
    *(float4*)&out[(m0 + r1) * 256 + j] = r;
  }
}

extern "C" void kernel_launch(void* const* d_in, const int* in_sizes, int n_in,
                              void* d_out, int out_size, void* d_ws, size_t ws_size,
                              hipStream_t stream) {
  (void)in_sizes; (void)n_in; (void)out_size; (void)ws_size;
  const float* iw      = (const float*)d_in[1];
  const float* anchor  = (const float*)d_in[2];
  const float* f0      = (const float*)d_in[3];
  const float* f1      = (const float*)d_in[4];
  const float* f2      = (const float*)d_in[5];
  const float* f3      = (const float*)d_in[6];
  const float* proj    = (const float*)d_in[7];
  const float* wh      = (const float*)d_in[8];
  const float* W_learn = (const float*)d_in[9];
  const float* b_learn = (const float*)d_in[10];
  const float* W_wts   = (const float*)d_in[11];
  const float* b_wts   = (const float*)d_in[12];
  const float* W_out   = (const float*)d_in[13];
  const float* b_out   = (const float*)d_in[14];
  float* out = (float*)d_out;
  float* ws = (float*)d_ws;
  unsigned short* featT = (unsigned short*)ws;   // bf16 element indices
  float* logits = ws + WS_LOGITS;
  float* feats  = ws + WS_FEATS;
  float* learn  = ws + WS_LEARN;

  k_transpose<<<dim3(6, 64, 48), 256, 0, stream>>>(f0, featT + FEATT_L0, 64, 176);
  k_transpose<<<dim3(3, 32, 48), 256, 0, stream>>>(f1, featT + FEATT_L1, 32, 88);
  k_transpose<<<dim3(2, 16, 48), 256, 0, stream>>>(f2, featT + FEATT_L2, 16, 44);
  k_transpose<<<dim3(1, 8, 48), 256, 0, stream>>>(f3, featT + FEATT_L3, 8, 22);
  k_wts_gemm<<<dim3(3, 256), 256, 0, stream>>>(iw, W_wts, b_wts, logits);
  k_learn<<<256, 256, 0, stream>>>(iw, W_learn, b_learn, learn);
  k_sample<<<4096, 256, 0, stream>>>(anchor, logits, learn, featT, proj, wh, feats);
  k_out_gemm<<<512, 256, 0, stream>>>(feats, W_out, b_out, iw, out);
}

// Round 5
// 398.137 us; speedup vs baseline: 1.7266x; 1.2361x over previous
//
#include <hip/hip_runtime.h>
#include <math.h>

// ---------------------------------------------------------------------------
// DeformableFeatureAggregation — MI355X
// Pipeline:
//   k_transpose x4 : feat (6,256,H,W) fp32 -> featT (6,H,W,256) bf16 (RTNE)
//   k_prep_a       : iw fp32 -> Ab bf16 (4096x256)
//   k_prep_b       : [W_wts | W_learn] -> Bb bf16 N-major (2560x256, 0-pad)
//   k_prep_w       : W_out -> Wob bf16 N-major (256x256)
//   k_wts_mfma     : MFMA GEMM -> logits bf16 (4096x2496) + learn fp32 (4096x18)
//                    (learnable-pts matvec folded in as columns 2496..2513)
//   k_sample       : per-anchor block: bf16 softmax, projection, task tables,
//                    bf16 bilinear gather -> feats bf16 (4096x256)
//   k_out_mfma     : MFMA GEMM out = feats @ W_out + b_out + iw (fp32 out)
// Workspace (float offsets):
//   featT   : ushorts 0..22978560        (float slots 0..11489280)
//   logitsB : ushorts at f11489280       (4096*2496)   -> f16601088
//   featsB  : ushorts at f16601088       (4096*256)    -> f17125376
//   learn   : floats  at f17125376       (4096*18)     -> f17199104
//   Ab      : ushorts at f17199104       (4096*256)    -> f17723392
//   Bb      : ushorts at f17723392       (2560*256)    -> f18051072
//   Wob     : ushorts at f18051072       (256*256)     -> f18083840 (~72 MB)
// ---------------------------------------------------------------------------

#define FEATT_L0 0
#define FEATT_L1 17301504
#define FEATT_L2 21626880
#define FEATT_L3 22708224
#define WS_LOGB 11489280
#define WS_FEATB 16601088
#define WS_LEARN 17125376
#define WS_AB 17199104
#define WS_BB 17723392
#define WS_WOB 18051072

typedef float v2f __attribute__((ext_vector_type(2)));
typedef __attribute__((ext_vector_type(8))) short bf16x8;
typedef __attribute__((ext_vector_type(4))) float f32x4;

__device__ const float FIXS[7][3] = {
    {0.f, 0.f, 0.f},  {0.45f, 0.f, 0.f}, {-0.45f, 0.f, 0.f}, {0.f, 0.45f, 0.f},
    {0.f, -0.45f, 0.f}, {0.f, 0.f, 0.45f}, {0.f, 0.f, -0.45f}};

__device__ __forceinline__ unsigned int f2bf(float f) {
  unsigned int u = __float_as_uint(f);
  u += 0x7fffu + ((u >> 16) & 1u);  // RTNE
  return u >> 16;
}
__device__ __forceinline__ float bf2f(unsigned short u) {
  return __uint_as_float(((unsigned int)u) << 16);
}

// (6,256,H,W) fp32 -> (6,H,W,256) bf16
__global__ __launch_bounds__(256) void k_transpose(const float* __restrict__ src,
                                                   unsigned short* __restrict__ dst,
                                                   int H, int W) {
  __shared__ float tile[32][33];
  const int tid = threadIdx.x;
  const int i = tid & 31;
  const int j = tid >> 5;
  const int xt = blockIdx.x * 32;
  const int y = blockIdx.y;
  const int c = blockIdx.z >> 3;
  const int cht = (blockIdx.z & 7) * 32;
#pragma unroll
  for (int jj = j; jj < 32; jj += 8) {
    int x = xt + i;
    float v = 0.f;
    if (x < W) v = src[((c * 256 + cht + jj) * H + y) * W + x];
    tile[jj][i] = v;
  }
  __syncthreads();
#pragma unroll
  for (int jj = j; jj < 32; jj += 8) {
    int x = xt + jj;
    if (x < W)
      dst[(((c * H + y) * W + x) * 256) + cht + i] = (unsigned short)f2bf(tile[i][jj]);
  }
}

// iw fp32 -> bf16, elementwise (1M elems, float4 -> packed 2x bf16x2)
__global__ __launch_bounds__(256) void k_prep_a(const float* __restrict__ src,
                                                unsigned short* __restrict__ dst) {
  const int i = blockIdx.x * 256 + threadIdx.x;
  const float4 v = ((const float4*)src)[i];
  uint2 o;
  o.x = f2bf(v.x) | (f2bf(v.y) << 16);
  o.y = f2bf(v.z) | (f2bf(v.w) << 16);
  ((uint2*)dst)[i] = o;
}

// Bb[j][k] = bf16( j<2496 ? W_wts[k][j] : j<2514 ? W_learn[k][j-2496] : 0 )
// 32x32 LDS tile transpose; grid (80, 8)
__global__ __launch_bounds__(256) void k_prep_b(const float* __restrict__ Ww,
                                                const float* __restrict__ Wl,
                                                unsigned short* __restrict__ Bb) {
  __shared__ unsigned short tile[32][33];
  const int tid = threadIdx.x;
  const int i = tid & 31;
  const int r = tid >> 5;
  const int j0 = blockIdx.x * 32;
  const int k0 = blockIdx.y * 32;
#pragma unroll
  for (int rr = r; rr < 32; rr += 8) {
    const int k = k0 + rr, j = j0 + i;
    float v = 0.f;
    if (j < 2496) v = Ww[k * 2496 + j];
    else if (j < 2514) v = Wl[k * 18 + (j - 2496)];
    tile[rr][i] = (unsigned short)f2bf(v);
  }
  __syncthreads();
#pragma unroll
  for (int rr = r; rr < 32; rr += 8)
    Bb[(j0 + rr) * 256 + k0 + i] = tile[i][rr];
}

// Wob[j][k] = bf16(W_out[k][j]) ; grid (8,8)
__global__ __launch_bounds__(256) void k_prep_w(const float* __restrict__ Wo,
                                                unsigned short* __restrict__ Wob) {
  __shared__ unsigned short tile[32][33];
  const int tid = threadIdx.x;
  const int i = tid & 31;
  const int r = tid >> 5;
  const int j0 = blockIdx.x * 32;
  const int k0 = blockIdx.y * 32;
#pragma unroll
  for (int rr = r; rr < 32; rr += 8)
    tile[rr][i] = (unsigned short)f2bf(Wo[(k0 + rr) * 256 + j0 + i]);
  __syncthreads();
#pragma unroll
  for (int rr = r; rr < 32; rr += 8)
    Wob[(j0 + rr) * 256 + k0 + i] = tile[i][rr];
}

// MFMA GEMM: [logits | learn] = Ab(4096x256) @ Bb^T + bias.
// 64x64 tile per block; wave w -> m-rows w*16..w*16+15, 4 n-subtiles.
// cols 0..2495 -> bf16 logits + b_wts; cols 2496..2513 -> sigmoid -> learn fp32.
__global__ __launch_bounds__(256) void k_wts_mfma(
    const unsigned short* __restrict__ Ab, const unsigned short* __restrict__ Bb,
    const float* __restrict__ b_wts, const float* __restrict__ b_learn,
    unsigned short* __restrict__ logitsB, float* __restrict__ learn) {
  const int tid = threadIdx.x;
  const int w = tid >> 6, lane = tid & 63;
  const int ml = lane & 15, q = lane >> 4;
  const int n0 = blockIdx.x * 64;
  const int m0 = blockIdx.y * 64;
  f32x4 acc[4] = {{0.f, 0.f, 0.f, 0.f}, {0.f, 0.f, 0.f, 0.f},
                  {0.f, 0.f, 0.f, 0.f}, {0.f, 0.f, 0.f, 0.f}};
  const unsigned short* Ap = Ab + (m0 + w * 16 + ml) * 256 + q * 8;
  const unsigned short* Bp = Bb + (n0 + ml) * 256 + q * 8;
#pragma unroll
  for (int kk = 0; kk < 8; ++kk) {
    const bf16x8 a = *(const bf16x8*)(Ap + kk * 32);
#pragma unroll
    for (int nt = 0; nt < 4; ++nt) {
      const bf16x8 b = *(const bf16x8*)(Bp + nt * 16 * 256 + kk * 32);
      acc[nt] = __builtin_amdgcn_mfma_f32_16x16x32_bf16(a, b, acc[nt], 0, 0, 0);
    }
  }
  const int rowb = m0 + w * 16 + q * 4;
#pragma unroll
  for (int nt = 0; nt < 4; ++nt) {
    const int col = n0 + nt * 16 + ml;
    if (col < 2496) {
      const float b = b_wts[col];
#pragma unroll
      for (int r = 0; r < 4; ++r)
        logitsB[(rowb + r) * 2496 + col] = (unsigned short)f2bf(acc[nt][r] + b);
    } else if (col < 2514) {
      const float b = b_learn[col - 2496];
#pragma unroll
      for (int r = 0; r < 4; ++r) {
        float v = fminf(fmaxf(acc[nt][r] + b, -9.21f), 9.21f);
        learn[(rowb + r) * 18 + (col - 2496)] = 1.f / (1.f + expf(-v)) - 0.5f;
      }
    }
  }
}

__global__ __launch_bounds__(256, 6) void k_sample(
    const float* __restrict__ anchor, const unsigned short* __restrict__ logitsB,
    const float* __restrict__ learn_g, const unsigned short* __restrict__ featT,
    const float* __restrict__ proj, const float* __restrict__ wh,
    unsigned short* __restrict__ featsB) {
  const int n = blockIdx.x;
  const int tid = threadIdx.x;
  const int lane = tid & 63;
  const int wave = tid >> 6;
  __shared__ unsigned short s_w[8 * 328];  // bf16 softmax weights [g][s]
  __shared__ float s_p2d[78][2];
  __shared__ float s_learn[18];
  __shared__ int4 s_off[312];    // corner BYTE offsets per task
  __shared__ float4 s_wt[312];   // bilinear corner weights per task
  __shared__ float s_red[4][256];

  // phase 1: bf16 logits -> transposed LDS; learn -> LDS
  for (int i = tid; i < 2496; i += 256) {
    const int s = i >> 3, g = i & 7;
    s_w[g * 328 + s] = logitsB[n * 2496 + i];
  }
  if (tid < 18) s_learn[tid] = learn_g[n * 18 + tid];
  __syncthreads();

  // phase 2: softmax over s (312) per group; wave w -> groups 2w, 2w+1
#pragma unroll
  for (int gg = 0; gg < 2; ++gg) {
    unsigned short* row = &s_w[(wave * 2 + gg) * 328];
    float l[5];
    float mx = -1e30f;
#pragma unroll
    for (int i = 0; i < 5; ++i) {
      const int s = lane + i * 64;
      l[i] = (s < 312) ? bf2f(row[s]) : -1e30f;
      mx = fmaxf(mx, l[i]);
    }
    for (int off = 32; off; off >>= 1) mx = fmaxf(mx, __shfl_xor(mx, off));
    float sum = 0.f;
#pragma unroll
    for (int i = 0; i < 5; ++i) {
      l[i] = __expf(l[i] - mx);
      sum += l[i];
    }
    for (int off = 32; off; off >>= 1) sum += __shfl_xor(sum, off);
    const float inv = 1.f / sum;
#pragma unroll
    for (int i = 0; i < 5; ++i) {
      const int s = lane + i * 64;
      if (s < 312) row[s] = (unsigned short)f2bf(l[i] * inv);
    }
  }

  // phase 3: projection of 78 (pt,cam) pairs
  if (tid < 78) {
    const int p = tid / 6, c = tid % 6;
    const float* an = anchor + n * 11;
    float qw = an[6], qx = an[7], qy = an[8], qz = an[9];
    const float qinv = 1.f / sqrtf(qw * qw + qx * qx + qy * qy + qz * qz);
    qw *= qinv; qx *= qinv; qy *= qinv; qz *= qinv;
    const float R00 = 1.f - 2.f * (qy * qy + qz * qz), R01 = 2.f * (qx * qy - qw * qz), R02 = 2.f * (qx * qz + qw * qy);
    const float R10 = 2.f * (qx * qy + qw * qz), R11 = 1.f - 2.f * (qx * qx + qz * qz), R12 = 2.f * (qy * qz - qw * qx);
    const float R20 = 2.f * (qx * qz - qw * qy), R21 = 2.f * (qy * qz + qw * qx), R22 = 1.f - 2.f * (qx * qx + qy * qy);
    float s0, s1, s2;
    if (p < 7) {
      s0 = FIXS[p][0]; s1 = FIXS[p][1]; s2 = FIXS[p][2];
    } else {
      const int b = (p - 7) * 3;
      s0 = s_learn[b]; s1 = s_learn[b + 1]; s2 = s_learn[b + 2];
    }
    const float vx = s0 * an[3], vy = s1 * an[4], vz = s2 * an[5];
    const float kx = R00 * vx + R10 * vy + R20 * vz + an[0];
    const float ky = R01 * vx + R11 * vy + R21 * vz + an[1];
    const float kz = R02 * vx + R12 * vy + R22 * vz + an[2];
    const float* P = proj + c * 16;
    const float h0 = P[0] * kx + P[1] * ky + P[2] * kz + P[3];
    const float h1 = P[4] * kx + P[5] * ky + P[6] * kz + P[7];
    const float h2 = P[8] * kx + P[9] * ky + P[10] * kz + P[11];
    const float zz = fmaxf(h2, 1e-5f);
    float px = h0 / zz / wh[c * 2 + 0];
    float py = h1 / zz / wh[c * 2 + 1];
    px = fminf(fmaxf(px, 0.f), 0.9999f);
    py = fminf(fmaxf(py, 0.f), 0.9999f);
    s_p2d[tid][0] = px;
    s_p2d[tid][1] = py;
  }
  __syncthreads();

  // phase 4: per-task (pc,l) corner BYTE offsets + bilinear weights
  {
    constexpr int LBB[4] = {0, 34603008, 43253760, 45416448};   // bytes
    constexpr int CSB[4] = {5767168, 1441792, 360448, 90112};    // H*W*512
    for (int t = tid; t < 312; t += 256) {
      const int pc = t >> 2, l = t & 3;
      const int c = pc % 6;
      const int H = 64 >> l, W = 176 >> l;
      const float fx = s_p2d[pc][0] * (float)W - 0.5f;
      const float fy = s_p2d[pc][1] * (float)H - 0.5f;
      const float x0f = floorf(fx), y0f = floorf(fy);
      const float wx = fx - x0f, wy = fy - y0f;
      const int x0 = (int)x0f, y0 = (int)y0f;
      const float mx0 = (x0 >= 0) ? 1.f : 0.f;
      const float mx1 = (x0 + 1 < W) ? 1.f : 0.f;
      const float my0 = (y0 >= 0) ? 1.f : 0.f;
      const float my1 = (y0 + 1 < H) ? 1.f : 0.f;
      const int cx0 = max(x0, 0), cx1 = min(x0 + 1, W - 1);
      const int cy0 = max(y0, 0), cy1 = min(y0 + 1, H - 1);
      const int base = LBB[l] + c * CSB[l];
      int4 o;
      o.x = base + (cy0 * W + cx0) * 512;
      o.y = base + (cy0 * W + cx1) * 512;
      o.z = base + (cy1 * W + cx0) * 512;
      o.w = base + (cy1 * W + cx1) * 512;
      s_off[t] = o;
      float4 w4;
      w4.x = (1.f - wx) * (1.f - wy) * mx0 * my0;
      w4.y = wx * (1.f - wy) * mx1 * my0;
      w4.z = (1.f - wx) * wy * mx0 * my1;
      w4.w = wx * wy * mx1 * my1;
      s_wt[t] = w4;
    }
  }
  __syncthreads();

  // phase 5: gather; packed-f32 blend (hi half keeps dirty mantissa, 2^-8 rel)
  v2f a01 = {0.f, 0.f}, a23 = {0.f, 0.f};
  const int chb = lane * 8;
  const int g = lane >> 3;
  const unsigned char* fb = (const unsigned char*)featT;
  const unsigned short* wrow = &s_w[g * 328];
  for (int pc = wave; pc < 78; pc += 4) {
    const int p = pc / 6, c = pc - p * 6;
    const int sb = c * 52 + p;
#pragma unroll
    for (int l4 = 0; l4 < 4; ++l4) {
      const int t = pc * 4 + l4;
      const int4 o = s_off[t];
      const float4 w = s_wt[t];
      const float wg = bf2f(wrow[sb + l4 * 13]);
      const uint2 u0 = *(const uint2*)(fb + (o.x + chb));
      const uint2 u1 = *(const uint2*)(fb + (o.y + chb));
      const uint2 u2 = *(const uint2*)(fb + (o.z + chb));
      const uint2 u3 = *(const uint2*)(fb + (o.w + chb));
      const float w0 = w.x * wg, w1 = w.y * wg, w2 = w.z * wg, w3 = w.w * wg;
      v2f p0, p1, p2, p3, q0, q1, q2, q3;
      p0.x = __uint_as_float(u0.x << 16); p0.y = __uint_as_float(u0.x);
      q0.x = __uint_as_float(u0.y << 16); q0.y = __uint_as_float(u0.y);
      p1.x = __uint_as_float(u1.x << 16); p1.y = __uint_as_float(u1.x);
      q1.x = __uint_as_float(u1.y << 16); q1.y = __uint_as_float(u1.y);
      p2.x = __uint_as_float(u2.x << 16); p2.y = __uint_as_float(u2.x);
      q2.x = __uint_as_float(u2.y << 16); q2.y = __uint_as_float(u2.y);
      p3.x = __uint_as_float(u3.x << 16); p3.y = __uint_as_float(u3.x);
      q3.x = __uint_as_float(u3.y << 16); q3.y = __uint_as_float(u3.y);
      a01 += p0 * w0; a23 += q0 * w0;
      a01 += p1 * w1; a23 += q1 * w1;
      a01 += p2 * w2; a23 += q2 * w2;
      a01 += p3 * w3; a23 += q3 * w3;
    }
  }
  const int ch4 = lane * 4;
  *(float4*)&s_red[wave][ch4] = make_float4(a01.x, a01.y, a23.x, a23.y);
  __syncthreads();
  if (wave == 0) {
    float4 r = make_float4(0.f, 0.f, 0.f, 0.f);
#pragma unroll
    for (int w2 = 0; w2 < 4; ++w2) {
      const float4 t = *(const float4*)&s_red[w2][ch4];
      r.x += t.x; r.y += t.y; r.z += t.z; r.w += t.w;
    }
    uint2 o;
    o.x = f2bf(r.x) | (f2bf(r.y) << 16);
    o.y = f2bf(r.z) | (f2bf(r.w) << 16);
    *(uint2*)&featsB[n * 256 + ch4] = o;
  }
}

// MFMA GEMM: out = featsB(4096x256) @ Wob^T + b_out + resid (fp32 out)
// 64x64 tile per block; grid (4, 64)
__global__ __launch_bounds__(256) void k_out_mfma(
    const unsigned short* __restrict__ Ab, const unsigned short* __restrict__ Bb,
    const float* __restrict__ bias, const float* __restrict__ resid,
    float* __restrict__ out) {
  const int tid = threadIdx.x;
  const int w = tid >> 6, lane = tid & 63;
  const int ml = lane & 15, q = lane >> 4;
  const int n0 = blockIdx.x * 64;
  const int m0 = blockIdx.y * 64;
  f32x4 acc[4] = {{0.f, 0.f, 0.f, 0.f}, {0.f, 0.f, 0.f, 0.f},
                  {0.f, 0.f, 0.f, 0.f}, {0.f, 0.f, 0.f, 0.f}};
  const unsigned short* Ap = Ab + (m0 + w * 16 + ml) * 256 + q * 8;
  const unsigned short* Bp = Bb + (n0 + ml) * 256 + q * 8;
#pragma unroll
  for (int kk = 0; kk < 8; ++kk) {
    const bf16x8 a = *(const bf16x8*)(Ap + kk * 32);
#pragma unroll
    for (int nt = 0; nt < 4; ++nt) {
      const bf16x8 b = *(const bf16x8*)(Bp + nt * 16 * 256 + kk * 32);
      acc[nt] = __builtin_amdgcn_mfma_f32_16x16x32_bf16(a, b, acc[nt], 0, 0, 0);
    }
  }
  const int rowb = m0 + w * 16 + q * 4;
#pragma unroll
  for (int nt = 0; nt < 4; ++nt) {
    const int col = n0 + nt * 16 + ml;
    const float b = bias[col];
#pragma unroll
    for (int r = 0; r < 4; ++r) {
      const int row = rowb + r;
      out[row * 256 + col] = acc[nt][r] + b + resid[row * 256 + col];
    }
  }
}

extern "C" void kernel_launch(void* const* d_in, const int* in_sizes, int n_in,
                              void* d_out, int out_size, void* d_ws, size_t ws_size,
                              hipStream_t stream) {
  (void)in_sizes; (void)n_in; (void)out_size; (void)ws_size;
  const float* iw      = (const float*)d_in[1];
  const float* anchor  = (const float*)d_in[2];
  const float* f0      = (const float*)d_in[3];
  const float* f1      = (const float*)d_in[4];
  const float* f2      = (const float*)d_in[5];
  const float* f3      = (const float*)d_in[6];
  const float* proj    = (const float*)d_in[7];
  const float* wh      = (const float*)d_in[8];
  const float* W_learn = (const float*)d_in[9];
  const float* b_learn = (const float*)d_in[10];
  const float* W_wts   = (const float*)d_in[11];
  const float* b_wts   = (const float*)d_in[12];
  const float* W_out   = (const float*)d_in[13];
  const float* b_out   = (const float*)d_in[14];
  float* out = (float*)d_out;
  float* ws = (float*)d_ws;
  unsigned short* featT   = (unsigned short*)ws;
  unsigned short* logitsB = (unsigned short*)(ws + WS_LOGB);
  unsigned short* featsB  = (unsigned short*)(ws + WS_FEATB);
  float*          learn   = ws + WS_LEARN;
  unsigned short* Ab      = (unsigned short*)(ws + WS_AB);
  unsigned short* Bb      = (unsigned short*)(ws + WS_BB);
  unsigned short* Wob     = (unsigned short*)(ws + WS_WOB);

  k_transpose<<<dim3(6, 64, 48), 256, 0, stream>>>(f0, featT + FEATT_L0, 64, 176);
  k_transpose<<<dim3(3, 32, 48), 256, 0, stream>>>(f1, featT + FEATT_L1, 32, 88);
  k_transpose<<<dim3(2, 16, 48), 256, 0, stream>>>(f2, featT + FEATT_L2, 16, 44);
  k_transpose<<<dim3(1, 8, 48), 256, 0, stream>>>(f3, featT + FEATT_L3, 8, 22);
  k_prep_a<<<1024, 256, 0, stream>>>(iw, Ab);
  k_prep_b<<<dim3(80, 8), 256, 0, stream>>>(W_wts, W_learn, Bb);
  k_prep_w<<<dim3(8, 8), 256, 0, stream>>>(W_out, Wob);
  k_wts_mfma<<<dim3(40, 64), 256, 0, stream>>>(Ab, Bb, b_wts, b_learn, logitsB, learn);
  k_sample<<<4096, 256, 0, stream>>>(anchor, logitsB, learn, featT, proj, wh, featsB);
  k_out_mfma<<<dim3(4, 64), 256, 0, stream>>>(featsB, Wob, b_out, iw, out);
}